// Round 2
// baseline (582.581 us; speedup 1.0000x reference)
//
#include <hip/hip_runtime.h>
#include <hip/hip_bf16.h>

#define N_NODES 100000
#define H_DIM   128
#define N_RELS  90
#define N_BASES 4
#define N_EDGES 800000
#define NROWT   6250           // N_NODES / 16
#define NCHUNK  4
#define CLOC    128            // c-cols per chunk (32 o's x 4 bases)
#define SCAN_NB 391            // ceil(100000/256)

typedef __attribute__((ext_vector_type(8))) short  short8;
typedef __attribute__((ext_vector_type(8))) __bf16 bf16x8;
typedef __attribute__((ext_vector_type(4))) float  floatx4;

// ---- workspace layout (bytes); total ~43 MB ----
#define FLAG_OFF   0
#define BMT_OFF    1024                        // 512*128 ushort = 131072
#define CNTS_OFF   132096                      // counts[100000] int = 400000
#define OFFS_OFF   532096                      // offsets[100000] int = 400000
#define CURS_OFF   932096                      // cursor[100000] int = 400000
#define BSUM_OFF   1332096                     // 391 int
#define BPRE_OFF   1333664                     // 391 int
#define SRCS_OFF   1335296                     // src_s[800000] int = 3200000
#define CNS_OFF    4535296                     // cn_s[800000] float4 = 12800000
#define XBC_OFF    17335296                    // xb_chunk 100000*128 ushort = 25600000
// end = 42935296

// ---------- helpers ----------
__device__ __forceinline__ float bs2f(unsigned short s) {
    union { unsigned u; float f; } x; x.u = ((unsigned)s) << 16; return x.f;
}
__device__ __forceinline__ unsigned short f2bs(float f) {
    unsigned u = __float_as_uint(f);
    return (unsigned short)((u + 0x7fffu + ((u >> 16) & 1u)) >> 16);   // RNE
}
__device__ __forceinline__ float ldf(const void* p, size_t i, int isbf) {
    return isbf ? bs2f(((const unsigned short*)p)[i]) : ((const float*)p)[i];
}
__device__ __forceinline__ bf16x8 load8(const void* p, size_t i, int isbf) {
    if (isbf) return *(const bf16x8*)((const unsigned short*)p + i);   // 16B load
    const float* f = (const float*)p + i;
    union { unsigned short u[8]; bf16x8 v; } r;
#pragma unroll
    for (int j = 0; j < 8; ++j) r.u[j] = f2bs(f[j]);
    return r.v;
}

// ---------- 0: detect float storage format (bf16 vs fp32) ----------
__global__ void detect_k(const void* norm, int* flag) {
    if (threadIdx.x == 0 && blockIdx.x == 0) {
        const unsigned* w = (const unsigned*)norm;
        int hits = 0;
        for (int i = 0; i < 16; ++i) {
            unsigned b1 = (w[i] >> 8) & 0xffu;   // high byte of elem0 if bf16-packed
            if (b1 >= 0x30u && b1 <= 0x3fu) hits++;
        }
        *flag = (hits >= 12) ? 1 : 0;
    }
}

// ---------- 1: BmatT[c=o*4+b][i] = weight[b][i][o]  (bf16) ----------
__global__ __launch_bounds__(256) void prep_bmt(const void* weight, unsigned short* bmt,
                                                const int* flag) {
    int isbf = *flag;
    int tid = blockIdx.x * 256 + threadIdx.x;      // 65536 total
    int c = tid >> 7, i = tid & 127;
    int o = c >> 2, b = c & 3;
    bmt[tid] = f2bs(ldf(weight, (size_t)b * 16384 + (size_t)i * 128 + o, isbf));
}

// ---------- 2: CSR-by-dst build ----------
__global__ __launch_bounds__(256) void count_k(const int* __restrict__ dst, int* __restrict__ counts) {
    int e = blockIdx.x * 256 + threadIdx.x;
    if (e < N_EDGES) atomicAdd(&counts[dst[e]], 1);
}

__global__ __launch_bounds__(256) void scanA(const int* __restrict__ counts,
                                             int* __restrict__ offs, int* __restrict__ bsum) {
    __shared__ int s[256];
    int t = threadIdx.x, i = blockIdx.x * 256 + t;
    int v = (i < N_NODES) ? counts[i] : 0;
    s[t] = v; __syncthreads();
    for (int off = 1; off < 256; off <<= 1) {
        int x = (t >= off) ? s[t - off] : 0;
        __syncthreads(); s[t] += x; __syncthreads();
    }
    if (i < N_NODES) offs[i] = s[t] - v;               // exclusive
    if (t == 255) bsum[blockIdx.x] = s[255];
}

__global__ __launch_bounds__(512) void scanB(const int* __restrict__ bsum, int* __restrict__ bpre) {
    __shared__ int s[512];
    int t = threadIdx.x;
    int v = (t < SCAN_NB) ? bsum[t] : 0;
    s[t] = v; __syncthreads();
    for (int off = 1; off < 512; off <<= 1) {
        int x = (t >= off) ? s[t - off] : 0;
        __syncthreads(); s[t] += x; __syncthreads();
    }
    if (t < SCAN_NB) bpre[t] = s[t] - v;               // exclusive
}

__global__ __launch_bounds__(256) void scanC(int* __restrict__ offs, const int* __restrict__ bpre,
                                             int* __restrict__ cursor) {
    int i = blockIdx.x * 256 + threadIdx.x;
    if (i < N_NODES) {
        int o = offs[i] + bpre[i >> 8];
        offs[i] = o; cursor[i] = o;
    }
}

__global__ __launch_bounds__(256) void fill_k(const int* __restrict__ r, const void* __restrict__ norm,
                                              const int* __restrict__ src, const int* __restrict__ dst,
                                              const void* __restrict__ wcomp,
                                              int* __restrict__ cursor,
                                              int* __restrict__ src_s, floatx4* __restrict__ cn_s,
                                              const int* flag) {
    int isbf = *flag;
    int e = blockIdx.x * 256 + threadIdx.x;
    if (e >= N_EDGES) return;
    int rel = r[e];
    float nm = ldf(norm, e, isbf);
    floatx4 cn;
    cn.x = ldf(wcomp, (size_t)rel * 4 + 0, isbf) * nm;
    cn.y = ldf(wcomp, (size_t)rel * 4 + 1, isbf) * nm;
    cn.z = ldf(wcomp, (size_t)rel * 4 + 2, isbf) * nm;
    cn.w = ldf(wcomp, (size_t)rel * 4 + 3, isbf) * nm;
    int pos = atomicAdd(&cursor[dst[e]], 1);
    src_s[pos] = src[e];
    cn_s[pos] = cn;
}

// ---------- 3: xbc[n][cl] = sum_i emb[h[n]][i] * BmatT[chunk*128+cl][i]  (MFMA) ----------
__global__ __launch_bounds__(256) void gemm_xb(const int* __restrict__ h,
                                               const void* __restrict__ emb,
                                               const unsigned short* __restrict__ bmt,
                                               unsigned short* __restrict__ xbc,
                                               const int* flag, int chunk) {
    int isbf = *flag;
    int lane = threadIdx.x & 63;
    int wave = (blockIdx.x * blockDim.x + threadIdx.x) >> 6;
    if (wave >= NROWT) return;
    int m = lane & 15;          // A row (node) within tile; C col (c-col) within tile
    int q = lane >> 4;          // quad
    size_t abase = (size_t)h[wave * 16 + m] * H_DIM;

    bf16x8 a0 = load8(emb, abase +  0 + q * 8, isbf);
    bf16x8 a1 = load8(emb, abase + 32 + q * 8, isbf);
    bf16x8 a2 = load8(emb, abase + 64 + q * 8, isbf);
    bf16x8 a3 = load8(emb, abase + 96 + q * 8, isbf);

    int ct0 = chunk * 8;
    for (int ct = ct0; ct < ct0 + 8; ++ct) {
        int col = ct * 16 + m;
        const unsigned short* bp = bmt + (size_t)col * 128 + q * 8;
        bf16x8 b0 = *(const bf16x8*)(bp);
        bf16x8 b1 = *(const bf16x8*)(bp + 32);
        bf16x8 b2 = *(const bf16x8*)(bp + 64);
        bf16x8 b3 = *(const bf16x8*)(bp + 96);
        floatx4 acc = {0.f, 0.f, 0.f, 0.f};
        acc = __builtin_amdgcn_mfma_f32_16x16x32_bf16(a0, b0, acc, 0, 0, 0);
        acc = __builtin_amdgcn_mfma_f32_16x16x32_bf16(a1, b1, acc, 0, 0, 0);
        acc = __builtin_amdgcn_mfma_f32_16x16x32_bf16(a2, b2, acc, 0, 0, 0);
        acc = __builtin_amdgcn_mfma_f32_16x16x32_bf16(a3, b3, acc, 0, 0, 0);
#pragma unroll
        for (int v = 0; v < 4; ++v) {   // C/D: node=(lane>>4)*4+v within tile, c=col
            xbc[(size_t)(wave * 16 + q * 4 + v) * CLOC + (col - chunk * CLOC)] = f2bs(acc[v]);
        }
    }
}

// ---------- 4: per-dst gather-reduce, direct out write ----------
__global__ __launch_bounds__(256) void reduce_k(const int* __restrict__ counts,
                                                const int* __restrict__ offs,
                                                const int* __restrict__ src_s,
                                                const floatx4* __restrict__ cn_s,
                                                const unsigned short* __restrict__ xbc,
                                                const void* __restrict__ bias,
                                                void* __restrict__ out,
                                                const int* flag, int chunk) {
    int isbf = *flag;
    int lane = threadIdx.x & 63;
    int wave = (blockIdx.x * blockDim.x + threadIdx.x) >> 6;
    int nw = (gridDim.x * blockDim.x) >> 6;
    int g = lane >> 4;          // edge slot 0..3
    int j = lane & 15;          // covers o_loc = 2j, 2j+1 (c_loc = j*8..j*8+7)
    for (int d = wave; d < N_NODES; d += nw) {
        int deg = counts[d], start = offs[d];
        float acc0 = 0.f, acc1 = 0.f;
        for (int base = 0; base < deg; base += 4) {
            int ei = base + g;
            bool valid = ei < deg;
            int sv = valid ? src_s[start + ei] : 0;
            floatx4 cn = valid ? cn_s[start + ei] : (floatx4){0.f, 0.f, 0.f, 0.f};
            short8 v = *(const short8*)(xbc + (size_t)sv * CLOC + j * 8);
            acc0 += cn.x * bs2f((unsigned short)v[0]) + cn.y * bs2f((unsigned short)v[1])
                  + cn.z * bs2f((unsigned short)v[2]) + cn.w * bs2f((unsigned short)v[3]);
            acc1 += cn.x * bs2f((unsigned short)v[4]) + cn.y * bs2f((unsigned short)v[5])
                  + cn.z * bs2f((unsigned short)v[6]) + cn.w * bs2f((unsigned short)v[7]);
        }
        acc0 += __shfl_down(acc0, 32); acc0 += __shfl_down(acc0, 16);
        acc1 += __shfl_down(acc1, 32); acc1 += __shfl_down(acc1, 16);
        if (lane < 16) {
            float inv = 1.0f / (float)(deg > 1 ? deg : 1);
            int o = chunk * 32 + 2 * j;
            float v0 = acc0 * inv + ldf(bias, o + 0, isbf);
            float v1 = acc1 * inv + ldf(bias, o + 1, isbf);
            size_t oi = (size_t)d * H_DIM + o;
            if (isbf) {
                unsigned pk = (unsigned)f2bs(v0) | ((unsigned)f2bs(v1) << 16);
                *(unsigned*)((unsigned short*)out + oi) = pk;
            } else {
                ((float*)out)[oi] = v0; ((float*)out)[oi + 1] = v1;
            }
        }
    }
}

extern "C" void kernel_launch(void* const* d_in, const int* in_sizes, int n_in,
                              void* d_out, int out_size, void* d_ws, size_t ws_size,
                              hipStream_t stream) {
    const int*  h      = (const int*)d_in[0];
    const int*  r      = (const int*)d_in[1];
    const void* norm   = d_in[2];
    const int*  src    = (const int*)d_in[3];
    const int*  dst    = (const int*)d_in[4];
    const void* emb    = d_in[5];
    const void* weight = d_in[6];
    const void* wcomp  = d_in[7];
    const void* bias   = d_in[8];

    char* ws = (char*)d_ws;
    int*            flag   = (int*)(ws + FLAG_OFF);
    unsigned short* bmt    = (unsigned short*)(ws + BMT_OFF);
    int*            counts = (int*)(ws + CNTS_OFF);
    int*            offs   = (int*)(ws + OFFS_OFF);
    int*            cursor = (int*)(ws + CURS_OFF);
    int*            bsum   = (int*)(ws + BSUM_OFF);
    int*            bpre   = (int*)(ws + BPRE_OFF);
    int*            src_s  = (int*)(ws + SRCS_OFF);
    floatx4*        cn_s   = (floatx4*)(ws + CNS_OFF);
    unsigned short* xbc    = (unsigned short*)(ws + XBC_OFF);

    // zero only counts (ws is poisoned 0xAA every call)
    hipMemsetAsync(counts, 0, N_NODES * sizeof(int), stream);

    detect_k<<<1, 64, 0, stream>>>(norm, flag);
    prep_bmt<<<256, 256, 0, stream>>>(weight, bmt, flag);
    count_k<<<(N_EDGES + 255) / 256, 256, 0, stream>>>(dst, counts);
    scanA<<<SCAN_NB, 256, 0, stream>>>(counts, offs, bsum);
    scanB<<<1, 512, 0, stream>>>(bsum, bpre);
    scanC<<<SCAN_NB, 256, 0, stream>>>(offs, bpre, cursor);
    fill_k<<<(N_EDGES + 255) / 256, 256, 0, stream>>>(r, norm, src, dst, wcomp,
                                                      cursor, src_s, cn_s, flag);
    for (int c = 0; c < NCHUNK; ++c) {
        gemm_xb<<<(NROWT + 3) / 4, 256, 0, stream>>>(h, emb, bmt, xbc, flag, c);
        reduce_k<<<4096, 256, 0, stream>>>(counts, offs, src_s, cn_s, xbc, bias,
                                           d_out, flag, c);
    }
}

// Round 3
// 406.293 us; speedup vs baseline: 1.4339x; 1.4339x over previous
//
#include <hip/hip_runtime.h>
#include <hip/hip_bf16.h>
#include <hip/hip_fp16.h>

#define N_NODES 100000
#define H_DIM   128
#define N_RELS  90
#define N_BASES 4
#define N_EDGES 800000
#define SCAN_NB 391            // ceil(100000/256)
#define NBLK    6250           // N_NODES / 16

typedef __attribute__((ext_vector_type(8))) __bf16 bf16x8;
typedef __attribute__((ext_vector_type(4))) float  floatx4;

// ---- workspace layout (bytes); total ~14.1 MB ----
#define FLAG_OFF   0
#define WT_OFF     1024                        // Wt[o][c] 128*512 ushort = 131072
#define CNTS_OFF   132096                      // counts[100000] int = 400000
#define OFFS_OFF   532096                      // offsets[100000] int = 400000
#define CURS_OFF   932096                      // cursor[100000] int = 400000
#define BSUM_OFF   1332096                     // 391 int
#define BPRE_OFF   1333664                     // 391 int
#define RECS_OFF   1335296                     // recs[800000] uint4 = 12800000
// end = 14135296

// ---------- helpers ----------
__device__ __forceinline__ float bs2f(unsigned short s) {
    union { unsigned u; float f; } x; x.u = ((unsigned)s) << 16; return x.f;
}
__device__ __forceinline__ unsigned short f2bs(float f) {
    unsigned u = __float_as_uint(f);
    return (unsigned short)((u + 0x7fffu + ((u >> 16) & 1u)) >> 16);   // RNE
}
__device__ __forceinline__ float ldf(const void* p, size_t i, int isbf) {
    return isbf ? bs2f(((const unsigned short*)p)[i]) : ((const float*)p)[i];
}

// ---------- 0: detect float storage format (bf16 vs fp32) ----------
__global__ void detect_k(const void* norm, int* flag) {
    if (threadIdx.x == 0 && blockIdx.x == 0) {
        const unsigned* w = (const unsigned*)norm;
        int hits = 0;
        for (int i = 0; i < 16; ++i) {
            unsigned b1 = (w[i] >> 8) & 0xffu;   // high byte of elem0 if bf16-packed
            if (b1 >= 0x30u && b1 <= 0x3fu) hits++;
        }
        *flag = (hits >= 12) ? 1 : 0;
    }
}

// ---------- 1: Wt[o][c=b*128+i] = weight[b][i][o]  (bf16, B^T layout) ----------
__global__ __launch_bounds__(256) void prep_wt(const void* weight, unsigned short* wt,
                                               const int* flag) {
    int isbf = *flag;
    int tid = blockIdx.x * 256 + threadIdx.x;      // 65536 total
    int o = tid >> 9, c = tid & 511;
    int b = c >> 7, i = c & 127;
    wt[tid] = f2bs(ldf(weight, (size_t)b * 16384 + (size_t)i * 128 + o, isbf));
}

// ---------- 2: CSR-by-dst build ----------
__global__ __launch_bounds__(256) void count_k(const int* __restrict__ dst, int* __restrict__ counts) {
    int e = blockIdx.x * 256 + threadIdx.x;
    if (e < N_EDGES) atomicAdd(&counts[dst[e]], 1);
}

__global__ __launch_bounds__(256) void scanA(const int* __restrict__ counts,
                                             int* __restrict__ offs, int* __restrict__ bsum) {
    __shared__ int s[256];
    int t = threadIdx.x, i = blockIdx.x * 256 + t;
    int v = (i < N_NODES) ? counts[i] : 0;
    s[t] = v; __syncthreads();
    for (int off = 1; off < 256; off <<= 1) {
        int x = (t >= off) ? s[t - off] : 0;
        __syncthreads(); s[t] += x; __syncthreads();
    }
    if (i < N_NODES) offs[i] = s[t] - v;               // exclusive
    if (t == 255) bsum[blockIdx.x] = s[255];
}

__global__ __launch_bounds__(512) void scanB(const int* __restrict__ bsum, int* __restrict__ bpre) {
    __shared__ int s[512];
    int t = threadIdx.x;
    int v = (t < SCAN_NB) ? bsum[t] : 0;
    s[t] = v; __syncthreads();
    for (int off = 1; off < 512; off <<= 1) {
        int x = (t >= off) ? s[t - off] : 0;
        __syncthreads(); s[t] += x; __syncthreads();
    }
    if (t < SCAN_NB) bpre[t] = s[t] - v;               // exclusive
}

__global__ __launch_bounds__(256) void scanC(int* __restrict__ offs, const int* __restrict__ bpre,
                                             int* __restrict__ cursor) {
    int i = blockIdx.x * 256 + threadIdx.x;
    if (i < N_NODES) {
        int o = offs[i] + bpre[i >> 8];
        offs[i] = o; cursor[i] = o;
    }
}

// ---------- 3: fill AoS records {h[src], c0..c3 as fp16x4} sorted by dst ----------
__global__ __launch_bounds__(256) void fill_k(const int* __restrict__ r, const void* __restrict__ norm,
                                              const int* __restrict__ src, const int* __restrict__ dst,
                                              const int* __restrict__ h,
                                              const void* __restrict__ wcomp,
                                              int* __restrict__ cursor,
                                              uint4* __restrict__ recs,
                                              const int* flag) {
    int isbf = *flag;
    int e = blockIdx.x * 256 + threadIdx.x;
    if (e >= N_EDGES) return;
    int rel = r[e];
    float nm = ldf(norm, e, isbf);
    float c0 = ldf(wcomp, (size_t)rel * 4 + 0, isbf) * nm;
    float c1 = ldf(wcomp, (size_t)rel * 4 + 1, isbf) * nm;
    float c2 = ldf(wcomp, (size_t)rel * 4 + 2, isbf) * nm;
    float c3 = ldf(wcomp, (size_t)rel * 4 + 3, isbf) * nm;
    uint4 rc;
    rc.x = (unsigned)h[src[e]];
    rc.y = (unsigned)__half_as_ushort(__float2half_rn(c0))
         | ((unsigned)__half_as_ushort(__float2half_rn(c1)) << 16);
    rc.z = (unsigned)__half_as_ushort(__float2half_rn(c2))
         | ((unsigned)__half_as_ushort(__float2half_rn(c3)) << 16);
    rc.w = 0u;
    int pos = atomicAdd(&cursor[dst[e]], 1);
    recs[pos] = rc;
}

// ---------- 4: fused gather-aggregate (input space) + MFMA basis GEMM ----------
// Per block: 16 dsts. Phase1: wave w accumulates y[d, b*128+i] for 4 dsts in regs
// (lane covers i=2*lane,2*lane+1), scales by 1/deg, writes bf16 to LDS.
// Phase2: y[16][512] x Wt^T[512][128] via 16x16x32 MFMA; wave w does col-tiles 2w,2w+1.
__global__ __launch_bounds__(256) void fused_k(const int* __restrict__ counts,
                                               const int* __restrict__ offs,
                                               const uint4* __restrict__ recs,
                                               const void* __restrict__ emb,
                                               const unsigned short* __restrict__ wt,
                                               const void* __restrict__ bias,
                                               void* __restrict__ out,
                                               const int* flag) {
    int isbf = *flag;
    __shared__ __align__(16) unsigned short y[16][520];   // +8 pad: conflict-free ds_read_b128
    int lane = threadIdx.x & 63;
    int w = threadIdx.x >> 6;
    int blk = blockIdx.x;

    // ---- phase 1: aggregate x[src] per dst, in input space ----
    for (int t = 0; t < 4; ++t) {
        int dloc = w * 4 + t;
        int d = blk * 16 + dloc;
        int deg = counts[d], start = offs[d];
        float inv = 1.0f / (float)(deg > 1 ? deg : 1);
        float a00 = 0.f, a01 = 0.f, a10 = 0.f, a11 = 0.f;
        float a20 = 0.f, a21 = 0.f, a30 = 0.f, a31 = 0.f;
        int e = 0;
        for (; e + 1 < deg; e += 2) {           // 2-edge unroll for MLP
            uint4 r0 = recs[start + e];
            uint4 r1 = recs[start + e + 1];
            float x00, x01, x10, x11;
            if (isbf) {
                unsigned p0 = *(const unsigned*)((const unsigned short*)emb + (size_t)r0.x * 128 + lane * 2);
                unsigned p1 = *(const unsigned*)((const unsigned short*)emb + (size_t)r1.x * 128 + lane * 2);
                x00 = bs2f((unsigned short)(p0 & 0xffffu)); x01 = bs2f((unsigned short)(p0 >> 16));
                x10 = bs2f((unsigned short)(p1 & 0xffffu)); x11 = bs2f((unsigned short)(p1 >> 16));
            } else {
                const float* f0 = (const float*)emb + (size_t)r0.x * 128 + lane * 2;
                const float* f1 = (const float*)emb + (size_t)r1.x * 128 + lane * 2;
                x00 = f0[0]; x01 = f0[1]; x10 = f1[0]; x11 = f1[1];
            }
            float2 c01a = __half22float2(*(const __half2*)&r0.y);
            float2 c23a = __half22float2(*(const __half2*)&r0.z);
            float2 c01b = __half22float2(*(const __half2*)&r1.y);
            float2 c23b = __half22float2(*(const __half2*)&r1.z);
            a00 += c01a.x * x00 + c01b.x * x10;  a01 += c01a.x * x01 + c01b.x * x11;
            a10 += c01a.y * x00 + c01b.y * x10;  a11 += c01a.y * x01 + c01b.y * x11;
            a20 += c23a.x * x00 + c23b.x * x10;  a21 += c23a.x * x01 + c23b.x * x11;
            a30 += c23a.y * x00 + c23b.y * x10;  a31 += c23a.y * x01 + c23b.y * x11;
        }
        if (e < deg) {
            uint4 r0 = recs[start + e];
            float x00, x01;
            if (isbf) {
                unsigned p0 = *(const unsigned*)((const unsigned short*)emb + (size_t)r0.x * 128 + lane * 2);
                x00 = bs2f((unsigned short)(p0 & 0xffffu)); x01 = bs2f((unsigned short)(p0 >> 16));
            } else {
                const float* f0 = (const float*)emb + (size_t)r0.x * 128 + lane * 2;
                x00 = f0[0]; x01 = f0[1];
            }
            float2 c01a = __half22float2(*(const __half2*)&r0.y);
            float2 c23a = __half22float2(*(const __half2*)&r0.z);
            a00 += c01a.x * x00;  a01 += c01a.x * x01;
            a10 += c01a.y * x00;  a11 += c01a.y * x01;
            a20 += c23a.x * x00;  a21 += c23a.x * x01;
            a30 += c23a.y * x00;  a31 += c23a.y * x01;
        }
        // y[dloc][b*128 + 2*lane .. +1]  (packed dword stores; 2 lanes/bank = free)
        *(unsigned*)&y[dloc][0 * 128 + 2 * lane] = (unsigned)f2bs(a00 * inv) | ((unsigned)f2bs(a01 * inv) << 16);
        *(unsigned*)&y[dloc][1 * 128 + 2 * lane] = (unsigned)f2bs(a10 * inv) | ((unsigned)f2bs(a11 * inv) << 16);
        *(unsigned*)&y[dloc][2 * 128 + 2 * lane] = (unsigned)f2bs(a20 * inv) | ((unsigned)f2bs(a21 * inv) << 16);
        *(unsigned*)&y[dloc][3 * 128 + 2 * lane] = (unsigned)f2bs(a30 * inv) | ((unsigned)f2bs(a31 * inv) << 16);
    }
    __syncthreads();

    // ---- phase 2: out[16 dsts][128] = y[16][512] x Wt^T, MFMA 16x16x32 ----
    int m = lane & 15;          // A row (dst) / B col (o) within tile
    int q = lane >> 4;          // quad: k = kc*32 + q*8 + j
    for (int half = 0; half < 2; ++half) {
        int ct = w * 2 + half;                   // col-tile 0..7
        floatx4 acc = {0.f, 0.f, 0.f, 0.f};
        const unsigned short* bp = wt + (size_t)(ct * 16 + m) * 512 + q * 8;
#pragma unroll
        for (int kc = 0; kc < 16; ++kc) {
            bf16x8 af = *(const bf16x8*)&y[m][kc * 32 + q * 8];
            bf16x8 bf = *(const bf16x8*)(bp + kc * 32);
            acc = __builtin_amdgcn_mfma_f32_16x16x32_bf16(af, bf, acc, 0, 0, 0);
        }
#pragma unroll
        for (int v = 0; v < 4; ++v) {            // C/D: row(dst)=q*4+v, col(o)=ct*16+m
            int o = ct * 16 + m;
            float val = acc[v] + ldf(bias, o, isbf);
            size_t oi = (size_t)(blk * 16 + q * 4 + v) * H_DIM + o;
            if (isbf) ((unsigned short*)out)[oi] = f2bs(val);
            else      ((float*)out)[oi] = val;
        }
    }
}

extern "C" void kernel_launch(void* const* d_in, const int* in_sizes, int n_in,
                              void* d_out, int out_size, void* d_ws, size_t ws_size,
                              hipStream_t stream) {
    const int*  h      = (const int*)d_in[0];
    const int*  r      = (const int*)d_in[1];
    const void* norm   = d_in[2];
    const int*  src    = (const int*)d_in[3];
    const int*  dst    = (const int*)d_in[4];
    const void* emb    = d_in[5];
    const void* weight = d_in[6];
    const void* wcomp  = d_in[7];
    const void* bias   = d_in[8];

    char* ws = (char*)d_ws;
    int*            flag   = (int*)(ws + FLAG_OFF);
    unsigned short* wt     = (unsigned short*)(ws + WT_OFF);
    int*            counts = (int*)(ws + CNTS_OFF);
    int*            offs   = (int*)(ws + OFFS_OFF);
    int*            cursor = (int*)(ws + CURS_OFF);
    int*            bsum   = (int*)(ws + BSUM_OFF);
    int*            bpre   = (int*)(ws + BPRE_OFF);
    uint4*          recs   = (uint4*)(ws + RECS_OFF);

    hipMemsetAsync(counts, 0, N_NODES * sizeof(int), stream);

    detect_k<<<1, 64, 0, stream>>>(norm, flag);
    prep_wt<<<256, 256, 0, stream>>>(weight, wt, flag);
    count_k<<<(N_EDGES + 255) / 256, 256, 0, stream>>>(dst, counts);
    scanA<<<SCAN_NB, 256, 0, stream>>>(counts, offs, bsum);
    scanB<<<1, 512, 0, stream>>>(bsum, bpre);
    scanC<<<SCAN_NB, 256, 0, stream>>>(offs, bpre, cursor);
    fill_k<<<(N_EDGES + 255) / 256, 256, 0, stream>>>(r, norm, src, dst, h, wcomp,
                                                      cursor, recs, flag);
    fused_k<<<NBLK, 256, 0, stream>>>(counts, offs, recs, emb, wt, bias, d_out, flag);
}

// Round 4
// 388.220 us; speedup vs baseline: 1.5006x; 1.0466x over previous
//
#include <hip/hip_runtime.h>
#include <hip/hip_bf16.h>
#include <hip/hip_fp16.h>

#define N_NODES 100000
#define H_DIM   128
#define N_RELS  90
#define N_BASES 4
#define N_EDGES 800000
#define SCAN_NB 391            // ceil(100000/256)
#define NBLK    6250           // N_NODES / 16

typedef __attribute__((ext_vector_type(8))) __bf16 bf16x8;
typedef __attribute__((ext_vector_type(4))) float  floatx4;

// ---- workspace layout (bytes); total ~17.3 MB ----
#define FLAG_OFF   0
#define WT_OFF     1024                        // Wt[o][c] 128*512 ushort = 131072
#define CNTS_OFF   132096                      // counts[100000] int = 400000
#define OFFS_OFF   532096                      // offsets[100000] int = 400000
#define CURS_OFF   932096                      // cursor[100000] int = 400000
#define BSUM_OFF   1332096                     // 391 int
#define BPRE_OFF   1333664                     // 391 int
#define PERM_OFF   1335296                     // perm[800000] int = 3200000
#define RECS_OFF   4535296                     // recs[800000] uint4 = 12800000
// end = 17335296

// ---------- helpers ----------
__device__ __forceinline__ float bs2f(unsigned short s) {
    union { unsigned u; float f; } x; x.u = ((unsigned)s) << 16; return x.f;
}
__device__ __forceinline__ unsigned short f2bs(float f) {
    unsigned u = __float_as_uint(f);
    return (unsigned short)((u + 0x7fffu + ((u >> 16) & 1u)) >> 16);   // RNE
}
__device__ __forceinline__ float ldf(const void* p, size_t i, int isbf) {
    return isbf ? bs2f(((const unsigned short*)p)[i]) : ((const float*)p)[i];
}

// ---------- 0: detect float storage format (bf16 vs fp32) ----------
__global__ void detect_k(const void* norm, int* flag) {
    if (threadIdx.x == 0 && blockIdx.x == 0) {
        const unsigned* w = (const unsigned*)norm;
        int hits = 0;
        for (int i = 0; i < 16; ++i) {
            unsigned b1 = (w[i] >> 8) & 0xffu;
            if (b1 >= 0x30u && b1 <= 0x3fu) hits++;
        }
        *flag = (hits >= 12) ? 1 : 0;
    }
}

// ---------- 1: Wt[o][c=b*128+i] = weight[b][i][o]  (bf16, B^T layout) ----------
__global__ __launch_bounds__(256) void prep_wt(const void* weight, unsigned short* wt,
                                               const int* flag) {
    int isbf = *flag;
    int tid = blockIdx.x * 256 + threadIdx.x;      // 65536 total
    int o = tid >> 9, c = tid & 511;
    int b = c >> 7, i = c & 127;
    wt[tid] = f2bs(ldf(weight, (size_t)b * 16384 + (size_t)i * 128 + o, isbf));
}

// ---------- 2: CSR-by-dst build ----------
__global__ __launch_bounds__(256) void count_k(const int* __restrict__ dst, int* __restrict__ counts) {
    int e = blockIdx.x * 256 + threadIdx.x;
    if (e < N_EDGES) atomicAdd(&counts[dst[e]], 1);
}

__global__ __launch_bounds__(256) void scanA(const int* __restrict__ counts,
                                             int* __restrict__ offs, int* __restrict__ bsum) {
    __shared__ int s[256];
    int t = threadIdx.x, i = blockIdx.x * 256 + t;
    int v = (i < N_NODES) ? counts[i] : 0;
    s[t] = v; __syncthreads();
    for (int off = 1; off < 256; off <<= 1) {
        int x = (t >= off) ? s[t - off] : 0;
        __syncthreads(); s[t] += x; __syncthreads();
    }
    if (i < N_NODES) offs[i] = s[t] - v;               // exclusive
    if (t == 255) bsum[blockIdx.x] = s[255];
}

__global__ __launch_bounds__(512) void scanB(const int* __restrict__ bsum, int* __restrict__ bpre) {
    __shared__ int s[512];
    int t = threadIdx.x;
    int v = (t < SCAN_NB) ? bsum[t] : 0;
    s[t] = v; __syncthreads();
    for (int off = 1; off < 512; off <<= 1) {
        int x = (t >= off) ? s[t - off] : 0;
        __syncthreads(); s[t] += x; __syncthreads();
    }
    if (t < SCAN_NB) bpre[t] = s[t] - v;               // exclusive
}

__global__ __launch_bounds__(256) void scanC(int* __restrict__ offs, const int* __restrict__ bpre,
                                             int* __restrict__ cursor) {
    int i = blockIdx.x * 256 + threadIdx.x;
    if (i < N_NODES) {
        int o = offs[i] + bpre[i >> 8];
        offs[i] = o; cursor[i] = o;
    }
}

// ---------- 3a: perm scatter (4B payload; far less write-allocate than 16B recs) ----
__global__ __launch_bounds__(256) void perm_k(const int* __restrict__ dst,
                                              int* __restrict__ cursor, int* __restrict__ perm) {
    int e = blockIdx.x * 256 + threadIdx.x;
    if (e < N_EDGES) {
        int pos = atomicAdd(&cursor[dst[e]], 1);
        perm[pos] = e;
    }
}

// ---------- 3b: build recs in CSR order with COALESCED writes ----------
__global__ __launch_bounds__(256) void recs_k(const int* __restrict__ perm,
                                              const int* __restrict__ r, const void* __restrict__ norm,
                                              const int* __restrict__ src, const int* __restrict__ h,
                                              const void* __restrict__ wcomp,
                                              uint4* __restrict__ recs, const int* flag) {
    int isbf = *flag;
    int i = blockIdx.x * 256 + threadIdx.x;
    if (i >= N_EDGES) return;
    int e = perm[i];
    int rel = r[e];
    float nm = ldf(norm, e, isbf);
    float c0 = ldf(wcomp, (size_t)rel * 4 + 0, isbf) * nm;
    float c1 = ldf(wcomp, (size_t)rel * 4 + 1, isbf) * nm;
    float c2 = ldf(wcomp, (size_t)rel * 4 + 2, isbf) * nm;
    float c3 = ldf(wcomp, (size_t)rel * 4 + 3, isbf) * nm;
    uint4 rc;
    rc.x = (unsigned)h[src[e]];
    rc.y = (unsigned)__half_as_ushort(__float2half_rn(c0))
         | ((unsigned)__half_as_ushort(__float2half_rn(c1)) << 16);
    rc.z = (unsigned)__half_as_ushort(__float2half_rn(c2))
         | ((unsigned)__half_as_ushort(__float2half_rn(c3)) << 16);
    rc.w = 0u;
    recs[i] = rc;
}

// ---------- 4: fused gather-aggregate (input space) + MFMA basis GEMM ----------
// Phase1 (slot-per-dst): wave w, slot g=lane>>4 owns dst blk*16+w*4+g; j=lane&15
// covers channels j*8..j*8+7 (16B row loads). 32 fp32 accs/lane, no cross-lane
// reduce. 2-edge unroll -> 8 independent row-gather chains per wave.
// Phase2: y[16][512] x Wt^T via 16x16x32 MFMA (unchanged from R3).
__global__ __launch_bounds__(256) void fused_k(const int* __restrict__ counts,
                                               const int* __restrict__ offs,
                                               const uint4* __restrict__ recs,
                                               const void* __restrict__ emb,
                                               const unsigned short* __restrict__ wt,
                                               const void* __restrict__ bias,
                                               void* __restrict__ out,
                                               const int* flag) {
    int isbf = *flag;
    __shared__ __align__(16) unsigned short y[16][520];
    int lane = threadIdx.x & 63;
    int w = threadIdx.x >> 6;
    int g = lane >> 4, j = lane & 15;
    int blk = blockIdx.x;
    int dloc = w * 4 + g;
    int d = blk * 16 + dloc;
    int deg = counts[d], start = offs[d];
    float inv = 1.0f / (float)(deg > 1 ? deg : 1);

    float acc[4][8];
#pragma unroll
    for (int b = 0; b < 4; ++b)
#pragma unroll
        for (int c = 0; c < 8; ++c) acc[b][c] = 0.f;

    // wave-uniform loop bound = max deg over the wave's 4 slots
    int kmax = __shfl(deg, 0);
    kmax = max(kmax, __shfl(deg, 16));
    kmax = max(kmax, __shfl(deg, 32));
    kmax = max(kmax, __shfl(deg, 48));

    for (int k = 0; k < kmax; k += 2) {
        bool v0 = k < deg, v1 = (k + 1) < deg;
        int i0 = v0 ? start + k : 0;
        int i1 = v1 ? start + k + 1 : 0;
        uint4 r0 = recs[i0];
        uint4 r1 = recs[i1];
        // row chunk loads (16B/lane, coalesced 256B per row)
        float x0[8], x1[8];
        if (isbf) {
            bf16x8 p0 = *(const bf16x8*)((const unsigned short*)emb + (size_t)r0.x * 128 + j * 8);
            bf16x8 p1 = *(const bf16x8*)((const unsigned short*)emb + (size_t)r1.x * 128 + j * 8);
#pragma unroll
            for (int c = 0; c < 8; ++c) { x0[c] = (float)p0[c]; x1[c] = (float)p1[c]; }
        } else {
            const floatx4* f0 = (const floatx4*)((const float*)emb + (size_t)r0.x * 128 + j * 8);
            const floatx4* f1 = (const floatx4*)((const float*)emb + (size_t)r1.x * 128 + j * 8);
            floatx4 a0 = f0[0], b0 = f0[1], a1 = f1[0], b1 = f1[1];
#pragma unroll
            for (int c = 0; c < 4; ++c) { x0[c] = a0[c]; x0[c + 4] = b0[c]; x1[c] = a1[c]; x1[c + 4] = b1[c]; }
        }
        float2 c01a = __half22float2(*(const __half2*)&r0.y);
        float2 c23a = __half22float2(*(const __half2*)&r0.z);
        float2 c01b = __half22float2(*(const __half2*)&r1.y);
        float2 c23b = __half22float2(*(const __half2*)&r1.z);
        float cf0[4] = {v0 ? c01a.x : 0.f, v0 ? c01a.y : 0.f, v0 ? c23a.x : 0.f, v0 ? c23a.y : 0.f};
        float cf1[4] = {v1 ? c01b.x : 0.f, v1 ? c01b.y : 0.f, v1 ? c23b.x : 0.f, v1 ? c23b.y : 0.f};
#pragma unroll
        for (int b = 0; b < 4; ++b)
#pragma unroll
            for (int c = 0; c < 8; ++c)
                acc[b][c] += cf0[b] * x0[c] + cf1[b] * x1[c];
    }

    // scale + pack to LDS: y[dloc][b*128 + j*8 .. +7]
#pragma unroll
    for (int b = 0; b < 4; ++b) {
        union { unsigned short u[8]; uint4 v; } pk;
#pragma unroll
        for (int c = 0; c < 8; ++c) pk.u[c] = f2bs(acc[b][c] * inv);
        *(uint4*)&y[dloc][b * 128 + j * 8] = pk.v;
    }
    __syncthreads();

    // ---- phase 2: out[16 dsts][128] = y[16][512] x Wt^T, MFMA 16x16x32 ----
    int m = lane & 15;          // A row (dst) / B col (o) within tile
    int q = lane >> 4;          // quad
    for (int half = 0; half < 2; ++half) {
        int ct = w * 2 + half;                   // col-tile 0..7
        floatx4 accm = {0.f, 0.f, 0.f, 0.f};
        const unsigned short* bp = wt + (size_t)(ct * 16 + m) * 512 + q * 8;
#pragma unroll
        for (int kc = 0; kc < 16; ++kc) {
            bf16x8 af = *(const bf16x8*)&y[m][kc * 32 + q * 8];
            bf16x8 bf = *(const bf16x8*)(bp + kc * 32);
            accm = __builtin_amdgcn_mfma_f32_16x16x32_bf16(af, bf, accm, 0, 0, 0);
        }
#pragma unroll
        for (int v = 0; v < 4; ++v) {            // C/D: row(dst)=q*4+v, col(o)=ct*16+m
            int o = ct * 16 + m;
            float val = accm[v] + ldf(bias, o, isbf);
            size_t oi = (size_t)(blk * 16 + q * 4 + v) * H_DIM + o;
            if (isbf) ((unsigned short*)out)[oi] = f2bs(val);
            else      ((float*)out)[oi] = val;
        }
    }
}

extern "C" void kernel_launch(void* const* d_in, const int* in_sizes, int n_in,
                              void* d_out, int out_size, void* d_ws, size_t ws_size,
                              hipStream_t stream) {
    const int*  h      = (const int*)d_in[0];
    const int*  r      = (const int*)d_in[1];
    const void* norm   = d_in[2];
    const int*  src    = (const int*)d_in[3];
    const int*  dst    = (const int*)d_in[4];
    const void* emb    = d_in[5];
    const void* weight = d_in[6];
    const void* wcomp  = d_in[7];
    const void* bias   = d_in[8];

    char* ws = (char*)d_ws;
    int*            flag   = (int*)(ws + FLAG_OFF);
    unsigned short* wt     = (unsigned short*)(ws + WT_OFF);
    int*            counts = (int*)(ws + CNTS_OFF);
    int*            offs   = (int*)(ws + OFFS_OFF);
    int*            cursor = (int*)(ws + CURS_OFF);
    int*            bsum   = (int*)(ws + BSUM_OFF);
    int*            bpre   = (int*)(ws + BPRE_OFF);
    int*            perm   = (int*)(ws + PERM_OFF);
    uint4*          recs   = (uint4*)(ws + RECS_OFF);

    hipMemsetAsync(counts, 0, N_NODES * sizeof(int), stream);

    detect_k<<<1, 64, 0, stream>>>(norm, flag);
    prep_wt<<<256, 256, 0, stream>>>(weight, wt, flag);
    count_k<<<(N_EDGES + 255) / 256, 256, 0, stream>>>(dst, counts);
    scanA<<<SCAN_NB, 256, 0, stream>>>(counts, offs, bsum);
    scanB<<<1, 512, 0, stream>>>(bsum, bpre);
    scanC<<<SCAN_NB, 256, 0, stream>>>(offs, bpre, cursor);
    perm_k<<<(N_EDGES + 255) / 256, 256, 0, stream>>>(dst, cursor, perm);
    recs_k<<<(N_EDGES + 255) / 256, 256, 0, stream>>>(perm, r, norm, src, h, wcomp,
                                                      recs, flag);
    fused_k<<<NBLK, 256, 0, stream>>>(counts, offs, recs, emb, wt, bias, d_out, flag);
}

// Round 6
// 355.272 us; speedup vs baseline: 1.6398x; 1.0927x over previous
//
#include <hip/hip_runtime.h>
#include <hip/hip_bf16.h>

#define N_NODES 100000
#define H_DIM   128
#define N_RELS  90
#define N_BASES 4
#define N_EDGES 800000
#define SCAN_NB 391            // ceil(100000/256)
#define NBLK    6250           // N_NODES / 16

typedef __attribute__((ext_vector_type(8))) __bf16 bf16x8;
typedef __attribute__((ext_vector_type(4))) float  floatx4;

// ---- workspace layout (bytes); total ~8.1 MB ----
#define WT_OFF     0                           // Wt[o][c] 128*512 ushort = 131072
#define CNTS_OFF   131072                      // counts[100000] int = 400000
#define OFFS_OFF   531072                      // offsets[100000] int = 400000
#define CURS_OFF   931072                      // cursor[100000] int = 400000
#define BSUM_OFF   1331072                     // 391 int
#define BPRE_OFF   1332672                     // 391 int
#define RECS_OFF   1334272                     // recs[800000] u64 = 6400000
// end = 7734272

// ---------- helpers ----------
__device__ __forceinline__ float bs2f(unsigned short s) {
    union { unsigned u; float f; } x; x.u = ((unsigned)s) << 16; return x.f;
}
__device__ __forceinline__ unsigned short f2bs(float f) {
    unsigned u = __float_as_uint(f);
    return (unsigned short)((u + 0x7fffu + ((u >> 16) & 1u)) >> 16);   // RNE
}
__device__ __forceinline__ float ldf(const void* p, size_t i, int isbf) {
    return isbf ? bs2f(((const unsigned short*)p)[i]) : ((const float*)p)[i];
}
// detect float storage format from norm[0..31] (uniform [0,1) data):
// if bf16-packed, bits 8..15 of each dword are a sign+exp byte 0x30..0x3f.
__device__ __forceinline__ int detect_bf(const void* norm) {
    const unsigned* w = (const unsigned*)norm;
    int hits = 0;
#pragma unroll
    for (int i = 0; i < 16; ++i) {
        unsigned b1 = (w[i] >> 8) & 0xffu;
        hits += (b1 >= 0x30u && b1 <= 0x3fu) ? 1 : 0;
    }
    return hits >= 12;
}

// ---------- 1: [merged] Wt repack + dst-degree count ----------
// blocks [0,256): Wt[o][c=b*128+i] = weight[b][i][o]; blocks [256,..): count
__global__ __launch_bounds__(256) void prep_count_k(const void* __restrict__ weight,
                                                    unsigned short* __restrict__ wt,
                                                    const int* __restrict__ dst,
                                                    int* __restrict__ counts,
                                                    const void* __restrict__ norm) {
    int b = blockIdx.x;
    if (b < 256) {
        int isbf = detect_bf(norm);
        int tid = b * 256 + threadIdx.x;           // 65536 total
        int o = tid >> 9, c = tid & 511;
        int bb = c >> 7, i = c & 127;
        wt[tid] = f2bs(ldf(weight, (size_t)bb * 16384 + (size_t)i * 128 + o, isbf));
    } else {
        int e = (b - 256) * 256 + threadIdx.x;
        if (e < N_EDGES) atomicAdd(&counts[dst[e]], 1);
    }
}

// ---------- 2: CSR scan ----------
__global__ __launch_bounds__(256) void scanA(const int* __restrict__ counts,
                                             int* __restrict__ offs, int* __restrict__ bsum) {
    __shared__ int s[256];
    int t = threadIdx.x, i = blockIdx.x * 256 + t;
    int v = (i < N_NODES) ? counts[i] : 0;
    s[t] = v; __syncthreads();
    for (int off = 1; off < 256; off <<= 1) {
        int x = (t >= off) ? s[t - off] : 0;
        __syncthreads(); s[t] += x; __syncthreads();
    }
    if (i < N_NODES) offs[i] = s[t] - v;               // exclusive
    if (t == 255) bsum[blockIdx.x] = s[255];
}

__global__ __launch_bounds__(512) void scanB(const int* __restrict__ bsum, int* __restrict__ bpre) {
    __shared__ int s[512];
    int t = threadIdx.x;
    int v = (t < SCAN_NB) ? bsum[t] : 0;
    s[t] = v; __syncthreads();
    for (int off = 1; off < 512; off <<= 1) {
        int x = (t >= off) ? s[t - off] : 0;
        __syncthreads(); s[t] += x; __syncthreads();
    }
    if (t < SCAN_NB) bpre[t] = s[t] - v;               // exclusive
}

__global__ __launch_bounds__(256) void scanC(int* __restrict__ offs, const int* __restrict__ bpre,
                                             int* __restrict__ cursor) {
    int i = blockIdx.x * 256 + threadIdx.x;
    if (i < N_NODES) {
        int o = offs[i] + bpre[i >> 8];
        offs[i] = o; cursor[i] = o;
    }
}

// ---------- 3: fill 8B records {h[src]|rel<<20, norm fp32} sorted by dst ----------
__global__ __launch_bounds__(256) void fill_k(const int* __restrict__ r, const void* __restrict__ norm,
                                              const int* __restrict__ src, const int* __restrict__ dst,
                                              const int* __restrict__ h,
                                              int* __restrict__ cursor,
                                              unsigned long long* __restrict__ recs) {
    int e = blockIdx.x * 256 + threadIdx.x;
    if (e >= N_EDGES) return;
    int isbf = detect_bf(norm);
    float nm = ldf(norm, e, isbf);
    unsigned lo = (unsigned)h[src[e]] | ((unsigned)r[e] << 20);   // h<2^20, rel<2^12
    unsigned long long rc = (unsigned long long)lo
                          | ((unsigned long long)__float_as_uint(nm) << 32);
    int pos = atomicAdd(&cursor[dst[e]], 1);
    __builtin_nontemporal_store(rc, &recs[pos]);
}

// ---------- 4: fused gather-aggregate (input space) + MFMA basis GEMM ----------
// Phase1 (slot-per-dst): wave w, slot g=lane>>4 owns dst blk*16+w*4+g; j=lane&15
// covers channels j*8..j*8+7 (16B row loads). 4-edge unroll + rec prefetch:
// 4 independent row loads + 4 rec loads in flight per lane.
// Phase2: y[16][512] x Wt^T via 16x16x32 MFMA.
__global__ __launch_bounds__(256) void fused_k(const int* __restrict__ counts,
                                               const int* __restrict__ offs,
                                               const unsigned long long* __restrict__ recs,
                                               const void* __restrict__ emb,
                                               const unsigned short* __restrict__ wt,
                                               const void* __restrict__ bias,
                                               const void* __restrict__ wcomp,
                                               const void* __restrict__ norm,
                                               void* __restrict__ out) {
    int isbf = detect_bf(norm);
    __shared__ float wc[N_RELS * 4];                      // 1440 B
    __shared__ __align__(16) unsigned short y[16][520];
    // N_RELS*4 = 360 > blockDim (256): MUST stride (R5 bug: single-shot load
    // left wc[256..359] uninitialized -> garbage coeffs for rel >= 64)
    for (int t = threadIdx.x; t < N_RELS * 4; t += 256) wc[t] = ldf(wcomp, t, isbf);
    __syncthreads();

    int t = threadIdx.x;
    int lane = t & 63;
    int w = t >> 6;
    int g = lane >> 4, j = lane & 15;
    int blk = blockIdx.x;
    int dloc = w * 4 + g;
    int d = blk * 16 + dloc;
    int deg = counts[d], start = offs[d];
    float inv = 1.0f / (float)(deg > 1 ? deg : 1);

    float acc[4][8];
#pragma unroll
    for (int b = 0; b < 4; ++b)
#pragma unroll
        for (int c = 0; c < 8; ++c) acc[b][c] = 0.f;

    // wave-uniform loop bound = max deg over the wave's 4 slots
    int kmax = __shfl(deg, 0);
    kmax = max(kmax, __shfl(deg, 16));
    kmax = max(kmax, __shfl(deg, 32));
    kmax = max(kmax, __shfl(deg, 48));

    unsigned long long rcur[4];
#pragma unroll
    for (int u = 0; u < 4; ++u) rcur[u] = recs[(u < deg) ? start + u : 0];

    for (int k = 0; k < kmax; k += 4) {
        // prefetch next 4 records
        unsigned long long rnext[4];
#pragma unroll
        for (int u = 0; u < 4; ++u) {
            int kk = k + 4 + u;
            rnext[u] = recs[(kk < deg) ? start + kk : 0];
        }
        // issue all 4 row loads (independent)
        bf16x8  rb[4];
        floatx4 rf[4][2];
        if (isbf) {
#pragma unroll
            for (int u = 0; u < 4; ++u) {
                unsigned hx = (unsigned)rcur[u] & 0xFFFFFu;
                rb[u] = *(const bf16x8*)((const unsigned short*)emb + (size_t)hx * 128 + j * 8);
            }
        } else {
#pragma unroll
            for (int u = 0; u < 4; ++u) {
                unsigned hx = (unsigned)rcur[u] & 0xFFFFFu;
                const floatx4* f = (const floatx4*)((const float*)emb + (size_t)hx * 128 + j * 8);
                rf[u][0] = f[0]; rf[u][1] = f[1];
            }
        }
        // consume
#pragma unroll
        for (int u = 0; u < 4; ++u) {
            bool v = (k + u) < deg;
            unsigned rel = ((unsigned)rcur[u] >> 20) & 0xFFFu;
            float nm = v ? __uint_as_float((unsigned)(rcur[u] >> 32)) : 0.f;
            const float* cw = &wc[rel * 4];
            float c0 = cw[0] * nm, c1 = cw[1] * nm, c2 = cw[2] * nm, c3 = cw[3] * nm;
            float x[8];
            if (isbf) {
#pragma unroll
                for (int c = 0; c < 8; ++c) x[c] = (float)rb[u][c];
            } else {
#pragma unroll
                for (int c = 0; c < 4; ++c) { x[c] = rf[u][0][c]; x[c + 4] = rf[u][1][c]; }
            }
#pragma unroll
            for (int c = 0; c < 8; ++c) {
                acc[0][c] += c0 * x[c];
                acc[1][c] += c1 * x[c];
                acc[2][c] += c2 * x[c];
                acc[3][c] += c3 * x[c];
            }
        }
#pragma unroll
        for (int u = 0; u < 4; ++u) rcur[u] = rnext[u];
    }

    // scale + pack to LDS: y[dloc][b*128 + j*8 .. +7]
#pragma unroll
    for (int b = 0; b < 4; ++b) {
        union { unsigned short u[8]; uint4 v; } pk;
#pragma unroll
        for (int c = 0; c < 8; ++c) pk.u[c] = f2bs(acc[b][c] * inv);
        *(uint4*)&y[dloc][b * 128 + j * 8] = pk.v;
    }
    __syncthreads();

    // ---- phase 2: out[16 dsts][128] = y[16][512] x Wt^T, MFMA 16x16x32 ----
    int m = lane & 15;          // A row (dst) / B col (o) within tile
    int q = lane >> 4;          // quad
    for (int half = 0; half < 2; ++half) {
        int ct = w * 2 + half;                   // col-tile 0..7
        floatx4 accm = {0.f, 0.f, 0.f, 0.f};
        const unsigned short* bp = wt + (size_t)(ct * 16 + m) * 512 + q * 8;
#pragma unroll
        for (int kc = 0; kc < 16; ++kc) {
            bf16x8 af = *(const bf16x8*)&y[m][kc * 32 + q * 8];
            bf16x8 bf = *(const bf16x8*)(bp + kc * 32);
            accm = __builtin_amdgcn_mfma_f32_16x16x32_bf16(af, bf, accm, 0, 0, 0);
        }
#pragma unroll
        for (int v = 0; v < 4; ++v) {            // C/D: row(dst)=q*4+v, col(o)=ct*16+m
            int o = ct * 16 + m;
            float val = accm[v] + ldf(bias, o, isbf);
            size_t oi = (size_t)(blk * 16 + q * 4 + v) * H_DIM + o;
            if (isbf) ((unsigned short*)out)[oi] = f2bs(val);
            else      ((float*)out)[oi] = val;
        }
    }
}

extern "C" void kernel_launch(void* const* d_in, const int* in_sizes, int n_in,
                              void* d_out, int out_size, void* d_ws, size_t ws_size,
                              hipStream_t stream) {
    const int*  h      = (const int*)d_in[0];
    const int*  r      = (const int*)d_in[1];
    const void* norm   = d_in[2];
    const int*  src    = (const int*)d_in[3];
    const int*  dst    = (const int*)d_in[4];
    const void* emb    = d_in[5];
    const void* weight = d_in[6];
    const void* wcomp  = d_in[7];
    const void* bias   = d_in[8];

    char* ws = (char*)d_ws;
    unsigned short*     wt     = (unsigned short*)(ws + WT_OFF);
    int*                counts = (int*)(ws + CNTS_OFF);
    int*                offs   = (int*)(ws + OFFS_OFF);
    int*                cursor = (int*)(ws + CURS_OFF);
    int*                bsum   = (int*)(ws + BSUM_OFF);
    int*                bpre   = (int*)(ws + BPRE_OFF);
    unsigned long long* recs   = (unsigned long long*)(ws + RECS_OFF);

    hipMemsetAsync(counts, 0, N_NODES * sizeof(int), stream);

    prep_count_k<<<256 + (N_EDGES + 255) / 256, 256, 0, stream>>>(weight, wt, dst, counts, norm);
    scanA<<<SCAN_NB, 256, 0, stream>>>(counts, offs, bsum);
    scanB<<<1, 512, 0, stream>>>(bsum, bpre);
    scanC<<<SCAN_NB, 256, 0, stream>>>(offs, bpre, cursor);
    fill_k<<<(N_EDGES + 255) / 256, 256, 0, stream>>>(r, norm, src, dst, h, cursor, recs);
    fused_k<<<NBLK, 256, 0, stream>>>(counts, offs, recs, emb, wt, bias, wcomp, norm, d_out);
}

// Round 7
// 337.729 us; speedup vs baseline: 1.7250x; 1.0519x over previous
//
#include <hip/hip_runtime.h>
#include <hip/hip_bf16.h>

#define N_NODES 100000
#define H_DIM   128
#define N_RELS  90
#define N_BASES 4
#define N_EDGES 800000
#define SCAN_NB 391            // ceil(100000/256)
#define NBLK    6250           // N_NODES / 16

typedef __attribute__((ext_vector_type(8))) __bf16 bf16x8;
typedef __attribute__((ext_vector_type(4))) float  floatx4;

// ---- workspace layout (bytes); total ~7.7 MB ----
#define WT_OFF     0                           // Wt[o][c] 128*512 ushort = 131072
#define CNTS_OFF   131072                      // counts[100000] int = 400000
#define OFFS_OFF   531072                      // offsets[100000] int = 400000
#define CURS_OFF   931072                      // cursor[100000] int = 400000
#define BSUM_OFF   1331072                     // 391 int
#define FLAG_OFF   1332672                     // 1 int
#define RECS_OFF   1334272                     // recs[800000] u64 = 6400000
// end = 7734272

// ---------- helpers ----------
__device__ __forceinline__ float bs2f(unsigned short s) {
    union { unsigned u; float f; } x; x.u = ((unsigned)s) << 16; return x.f;
}
__device__ __forceinline__ unsigned short f2bs(float f) {
    unsigned u = __float_as_uint(f);
    return (unsigned short)((u + 0x7fffu + ((u >> 16) & 1u)) >> 16);   // RNE
}
__device__ __forceinline__ float ldf(const void* p, size_t i, int isbf) {
    return isbf ? bs2f(((const unsigned short*)p)[i]) : ((const float*)p)[i];
}
// detect float storage format from norm[0..31] (uniform [0,1) data):
// if bf16-packed, bits 8..15 of each dword are a sign+exp byte 0x30..0x3f.
__device__ __forceinline__ int detect_bf(const void* norm) {
    const unsigned* w = (const unsigned*)norm;
    int hits = 0;
#pragma unroll
    for (int i = 0; i < 16; ++i) {
        unsigned b1 = (w[i] >> 8) & 0xffu;
        hits += (b1 >= 0x30u && b1 <= 0x3fu) ? 1 : 0;
    }
    return hits >= 12;
}

// ---------- 1: [merged] Wt repack + dst-degree count + flag ----------
__global__ __launch_bounds__(256) void prep_count_k(const void* __restrict__ weight,
                                                    unsigned short* __restrict__ wt,
                                                    const int* __restrict__ dst,
                                                    int* __restrict__ counts,
                                                    const void* __restrict__ norm,
                                                    int* __restrict__ flag) {
    int b = blockIdx.x;
    if (b == 0 && threadIdx.x == 0) *flag = detect_bf(norm);
    if (b < 256) {
        int isbf = detect_bf(norm);
        int tid = b * 256 + threadIdx.x;           // 65536 total
        int o = tid >> 9, c = tid & 511;
        int bb = c >> 7, i = c & 127;
        wt[tid] = f2bs(ldf(weight, (size_t)bb * 16384 + (size_t)i * 128 + o, isbf));
    } else {
        int e = (b - 256) * 256 + threadIdx.x;
        if (e < N_EDGES) atomicAdd(&counts[dst[e]], 1);
    }
}

// ---------- 2: CSR scan ----------
__global__ __launch_bounds__(256) void scanA(const int* __restrict__ counts,
                                             int* __restrict__ offs, int* __restrict__ bsum) {
    __shared__ int s[256];
    int t = threadIdx.x, i = blockIdx.x * 256 + t;
    int v = (i < N_NODES) ? counts[i] : 0;
    s[t] = v; __syncthreads();
    for (int off = 1; off < 256; off <<= 1) {
        int x = (t >= off) ? s[t - off] : 0;
        __syncthreads(); s[t] += x; __syncthreads();
    }
    if (i < N_NODES) offs[i] = s[t] - v;               // exclusive
    if (t == 255) bsum[blockIdx.x] = s[255];
}

// scanC2: block b computes prefix = sum(bsum[0..b-1]) inline (L2-hot), then
// finalizes offs and cursor. Replaces the old scanB+scanC pair.
__global__ __launch_bounds__(256) void scanC2(int* __restrict__ offs,
                                              const int* __restrict__ bsum,
                                              int* __restrict__ cursor) {
    int b = blockIdx.x, t = threadIdx.x;
    int v = 0;
    if (t < b) v = bsum[t];                     // SCAN_NB=391 < 512
    if (t + 256 < b) v += bsum[t + 256];
    v += __shfl_down(v, 32); v += __shfl_down(v, 16);
    v += __shfl_down(v, 8);  v += __shfl_down(v, 4);
    v += __shfl_down(v, 2);  v += __shfl_down(v, 1);
    __shared__ int wsum[4];
    __shared__ int sprefix;
    if ((t & 63) == 0) wsum[t >> 6] = v;
    __syncthreads();
    if (t == 0) sprefix = wsum[0] + wsum[1] + wsum[2] + wsum[3];
    __syncthreads();
    int i = b * 256 + t;
    if (i < N_NODES) {
        int o = offs[i] + sprefix;
        offs[i] = o; cursor[i] = o;
    }
}

// ---------- 3: fill 8B records {h[src]|rel<<20, norm fp32} sorted by dst ----------
__global__ __launch_bounds__(256) void fill_k(const int* __restrict__ r, const void* __restrict__ norm,
                                              const int* __restrict__ src, const int* __restrict__ dst,
                                              const int* __restrict__ h,
                                              int* __restrict__ cursor,
                                              unsigned long long* __restrict__ recs) {
    int e = blockIdx.x * 256 + threadIdx.x;
    if (e >= N_EDGES) return;
    int isbf = detect_bf(norm);
    float nm = ldf(norm, e, isbf);
    unsigned lo = (unsigned)h[src[e]] | ((unsigned)r[e] << 20);   // h<2^20, rel<2^12
    unsigned long long rc = (unsigned long long)lo
                          | ((unsigned long long)__float_as_uint(nm) << 32);
    int pos = atomicAdd(&cursor[dst[e]], 1);
    __builtin_nontemporal_store(rc, &recs[pos]);
}

// ---------- 4: fused gather-aggregate + MFMA basis GEMM, dtype-specialized ----------
// Phase1 (slot-per-dst): wave w, slot g=lane>>4 owns dst blk*16+w*4+g; j=lane&15
// covers channels j*8..j*8+7 (16B row loads). 4-edge unroll + rec prefetch.
// ISBF template kills the dead fallback path's registers (R6: 84 VGPR -> occ 31%).
template <int ISBF>
__global__ __launch_bounds__(256) void fused_k(const int* __restrict__ counts,
                                               const int* __restrict__ offs,
                                               const unsigned long long* __restrict__ recs,
                                               const void* __restrict__ emb,
                                               const unsigned short* __restrict__ wt,
                                               const void* __restrict__ bias,
                                               const void* __restrict__ wcomp,
                                               const int* __restrict__ flag,
                                               void* __restrict__ out) {
    if ((*flag != 0) != (ISBF != 0)) return;    // wrong dtype specialization
    __shared__ float wc[N_RELS * 4];                      // 1440 B
    __shared__ __align__(16) unsigned short y[16][520];
    // 360 > 256: MUST stride (R5 bug)
    for (int t = threadIdx.x; t < N_RELS * 4; t += 256) wc[t] = ldf(wcomp, t, ISBF);
    __syncthreads();

    int t = threadIdx.x;
    int lane = t & 63;
    int w = t >> 6;
    int g = lane >> 4, j = lane & 15;
    int blk = blockIdx.x;
    int dloc = w * 4 + g;
    int d = blk * 16 + dloc;
    int deg = counts[d], start = offs[d];
    float inv = 1.0f / (float)(deg > 1 ? deg : 1);

    float acc[4][8];
#pragma unroll
    for (int b = 0; b < 4; ++b)
#pragma unroll
        for (int c = 0; c < 8; ++c) acc[b][c] = 0.f;

    // wave-uniform loop bound = max deg over the wave's 4 slots
    int kmax = __shfl(deg, 0);
    kmax = max(kmax, __shfl(deg, 16));
    kmax = max(kmax, __shfl(deg, 32));
    kmax = max(kmax, __shfl(deg, 48));

    unsigned long long rcur[4];
#pragma unroll
    for (int u = 0; u < 4; ++u)
        rcur[u] = __builtin_nontemporal_load(&recs[(u < deg) ? start + u : 0]);

    for (int k = 0; k < kmax; k += 4) {
        // prefetch next 4 records
        unsigned long long rnext[4];
#pragma unroll
        for (int u = 0; u < 4; ++u) {
            int kk = k + 4 + u;
            rnext[u] = __builtin_nontemporal_load(&recs[(kk < deg) ? start + kk : 0]);
        }
        // issue all 4 row loads (independent; 16 rows in flight per wave)
        bf16x8  rb[4];
        floatx4 rf[4][2];
        if (ISBF) {
#pragma unroll
            for (int u = 0; u < 4; ++u) {
                unsigned hx = (unsigned)rcur[u] & 0xFFFFFu;
                rb[u] = *(const bf16x8*)((const unsigned short*)emb + (size_t)hx * 128 + j * 8);
            }
        } else {
#pragma unroll
            for (int u = 0; u < 4; ++u) {
                unsigned hx = (unsigned)rcur[u] & 0xFFFFFu;
                const floatx4* f = (const floatx4*)((const float*)emb + (size_t)hx * 128 + j * 8);
                rf[u][0] = f[0]; rf[u][1] = f[1];
            }
        }
        // consume
#pragma unroll
        for (int u = 0; u < 4; ++u) {
            bool v = (k + u) < deg;
            unsigned rel = ((unsigned)rcur[u] >> 20) & 0xFFFu;
            float nm = v ? __uint_as_float((unsigned)(rcur[u] >> 32)) : 0.f;
            const float* cw = &wc[rel * 4];
            float c0 = cw[0] * nm, c1 = cw[1] * nm, c2 = cw[2] * nm, c3 = cw[3] * nm;
            float x[8];
            if (ISBF) {
#pragma unroll
                for (int c = 0; c < 8; ++c) x[c] = (float)rb[u][c];
            } else {
#pragma unroll
                for (int c = 0; c < 4; ++c) { x[c] = rf[u][0][c]; x[c + 4] = rf[u][1][c]; }
            }
#pragma unroll
            for (int c = 0; c < 8; ++c) {
                acc[0][c] += c0 * x[c];
                acc[1][c] += c1 * x[c];
                acc[2][c] += c2 * x[c];
                acc[3][c] += c3 * x[c];
            }
        }
#pragma unroll
        for (int u = 0; u < 4; ++u) rcur[u] = rnext[u];
    }

    // scale + pack to LDS: y[dloc][b*128 + j*8 .. +7]
#pragma unroll
    for (int b = 0; b < 4; ++b) {
        union { unsigned short u[8]; uint4 v; } pk;
#pragma unroll
        for (int c = 0; c < 8; ++c) pk.u[c] = f2bs(acc[b][c] * inv);
        *(uint4*)&y[dloc][b * 128 + j * 8] = pk.v;
    }
    __syncthreads();

    // ---- phase 2: out[16 dsts][128] = y[16][512] x Wt^T, MFMA 16x16x32 ----
    int m = lane & 15;          // A row (dst) / B col (o) within tile
    int q = lane >> 4;          // quad
    for (int half = 0; half < 2; ++half) {
        int ct = w * 2 + half;                   // col-tile 0..7
        floatx4 accm = {0.f, 0.f, 0.f, 0.f};
        const unsigned short* bp = wt + (size_t)(ct * 16 + m) * 512 + q * 8;
#pragma unroll
        for (int kc = 0; kc < 16; ++kc) {
            bf16x8 af = *(const bf16x8*)&y[m][kc * 32 + q * 8];
            bf16x8 bf = *(const bf16x8*)(bp + kc * 32);
            accm = __builtin_amdgcn_mfma_f32_16x16x32_bf16(af, bf, accm, 0, 0, 0);
        }
#pragma unroll
        for (int v = 0; v < 4; ++v) {            // C/D: row(dst)=q*4+v, col(o)=ct*16+m
            int o = ct * 16 + m;
            float val = accm[v] + ldf(bias, o, ISBF);
            size_t oi = (size_t)(blk * 16 + q * 4 + v) * H_DIM + o;
            if (ISBF) __builtin_nontemporal_store(f2bs(val), (unsigned short*)out + oi);
            else      __builtin_nontemporal_store(val, (float*)out + oi);
        }
    }
}

extern "C" void kernel_launch(void* const* d_in, const int* in_sizes, int n_in,
                              void* d_out, int out_size, void* d_ws, size_t ws_size,
                              hipStream_t stream) {
    const int*  h      = (const int*)d_in[0];
    const int*  r      = (const int*)d_in[1];
    const void* norm   = d_in[2];
    const int*  src    = (const int*)d_in[3];
    const int*  dst    = (const int*)d_in[4];
    const void* emb    = d_in[5];
    const void* weight = d_in[6];
    const void* wcomp  = d_in[7];
    const void* bias   = d_in[8];

    char* ws = (char*)d_ws;
    unsigned short*     wt     = (unsigned short*)(ws + WT_OFF);
    int*                counts = (int*)(ws + CNTS_OFF);
    int*                offs   = (int*)(ws + OFFS_OFF);
    int*                cursor = (int*)(ws + CURS_OFF);
    int*                bsum   = (int*)(ws + BSUM_OFF);
    int*                flag   = (int*)(ws + FLAG_OFF);
    unsigned long long* recs   = (unsigned long long*)(ws + RECS_OFF);

    hipMemsetAsync(counts, 0, N_NODES * sizeof(int), stream);

    prep_count_k<<<256 + (N_EDGES + 255) / 256, 256, 0, stream>>>(weight, wt, dst, counts,
                                                                  norm, flag);
    scanA<<<SCAN_NB, 256, 0, stream>>>(counts, offs, bsum);
    scanC2<<<SCAN_NB, 256, 0, stream>>>(offs, bsum, cursor);
    fill_k<<<(N_EDGES + 255) / 256, 256, 0, stream>>>(r, norm, src, dst, h, cursor, recs);
    fused_k<1><<<NBLK, 256, 0, stream>>>(counts, offs, recs, emb, wt, bias, wcomp, flag, d_out);
    fused_k<0><<<NBLK, 256, 0, stream>>>(counts, offs, recs, emb, wt, bias, wcomp, flag, d_out);
}